// Round 2
// baseline (238.749 us; speedup 1.0000x reference)
//
#include <hip/hip_runtime.h>
#include <math.h>

// Shapes (fixed by the problem)
#define Hn 8
#define Sn 1024
#define Dn 64
#define KG 10

// Bias-table parameters: dist in [0,10), energy in [0,5)
#define TN   4096
#define RD   10.25f
#define RE   5.125f

typedef __attribute__((ext_vector_type(8))) short bf16x8;
typedef __attribute__((ext_vector_type(4))) float f32x4;
typedef unsigned short u16;
typedef unsigned int u32;

__device__ inline float bf2f(u16 u) {
    union { u32 i; float f; } v;
    v.i = ((u32)u) << 16;
    return v.f;
}

__device__ inline u16 f2bf(float f) {
    union { float f; u32 i; } v;
    v.f = f;
    u32 i = v.i;
    return (u16)((i + 0x7FFFu + ((i >> 16) & 1u)) >> 16);   // RNE
}

__device__ inline bf16x8 pack8(float4 a, float4 b) {
    bf16x8 r;
    r[0] = (short)f2bf(a.x); r[1] = (short)f2bf(a.y);
    r[2] = (short)f2bf(a.z); r[3] = (short)f2bf(a.w);
    r[4] = (short)f2bf(b.x); r[5] = (short)f2bf(b.y);
    r[6] = (short)f2bf(b.z); r[7] = (short)f2bf(b.w);
    return r;
}

// ---------------------------------------------------------------------------
// RBF (10 gaussians) -> 10x10 MLP (exact gelu) -> scalar, all f32.
// ---------------------------------------------------------------------------
__device__ float bias_eval(float x,
                           const float* __restrict__ mu, const float* __restrict__ sg,
                           const float* __restrict__ bb,
                           const float* __restrict__ W1, const float* __restrict__ b1,
                           const float* __restrict__ W2, const float* __restrict__ b2) {
    const float inv_s2pi = 0.39894228040143267794f;
    float psi[KG];
#pragma unroll
    for (int k = 0; k < KG; k++) {
        float s = sg[k];
        float z = (x + bb[k] - mu[k]) / s;
        psi[k] = __expf(-0.5f * z * z) * (inv_s2pi / s);
    }
    float out = b2[0];
#pragma unroll
    for (int l = 0; l < KG; l++) {
        float a = b1[l];
#pragma unroll
        for (int k = 0; k < KG; k++) a += psi[k] * W1[l * KG + k];
        float g = 0.5f * a * (1.0f + erff(a * 0.70710678118654752440f));
        out += g * W2[l];
    }
    return out;
}

// ---------------------------------------------------------------------------
// Kernel 1: build two 4096-entry interpolation tables (dist, energy).
// Entry i: low16 = bf16(f(x_i)), high16 = bf16(f(x_{i+1}) - f(x_i)).
// tab[0..4095] = dist table, tab[4096..8191] = energy table.
// ---------------------------------------------------------------------------
__global__ __launch_bounds__(256) void build_tables_kernel(
    const float* __restrict__ muD, const float* __restrict__ sgD, const float* __restrict__ bD,
    const float* __restrict__ muE, const float* __restrict__ sgE, const float* __restrict__ bE,
    const float* __restrict__ W1, const float* __restrict__ b1,
    const float* __restrict__ W2, const float* __restrict__ b2,
    u32* __restrict__ tab)
{
    int id = blockIdx.x * blockDim.x + threadIdx.x;   // 0 .. 8191
    int which = id >> 12;
    int idx   = id & (TN - 1);
    float h = (which ? RE : RD) / (float)TN;
    float x0 = idx * h;

    float v0, v1;
    if (which) {
        v0 = bias_eval(x0,     muE, sgE, bE, W1, b1, W2, b2);
        v1 = bias_eval(x0 + h, muE, sgE, bE, W1, b1, W2, b2);
    } else {
        v0 = bias_eval(x0,     muD, sgD, bD, W1, b1, W2, b2);
        v1 = bias_eval(x0 + h, muD, sgD, bD, W1, b1, W2, b2);
    }
    tab[id] = (u32)f2bf(v0) | ((u32)f2bf(v1 - v0) << 16);
}

__device__ inline float lerp_tab(const u32* __restrict__ st, float x, float invh) {
    float tf = x * invh;
    int i = (int)tf;
    i = max(0, min(i, TN - 1));
    float fr = tf - (float)i;
    u32 p = st[i];
    return fmaf(bf2f((u16)(p >> 16)), fr, bf2f((u16)p));
}

// ---------------------------------------------------------------------------
// Kernel 2: fused flash-style attention, f32 in / f32 out, bf16 MFMA inside.
// Grid: (S/16, H). Block: 256 threads = 4 waves.
// WG owns 16 q-rows of one head; wave w covers k-range [w*256,(w+1)*256);
// single cross-wave combine at the end (flash-2).
// ---------------------------------------------------------------------------
__global__ __launch_bounds__(256) void attn_kernel(
    const float* __restrict__ Q, const float* __restrict__ K, const float* __restrict__ V,
    const float* __restrict__ Dm, const float* __restrict__ Em, const int* __restrict__ Mk,
    const u32* __restrict__ gtab, float* __restrict__ out)
{
    __shared__ __align__(16) u32 sTab[2 * TN];          // 32 KB
    __shared__ float sOpart[4][16][Dn];                 // 16 KB
    __shared__ __align__(16) u16 sP[4][16 * 32];        // 4 KB
    __shared__ float sM[4][16], sL[4][16];

    const int tid = threadIdx.x;

    // stage bias tables into LDS (2048 uint4 = 8 per thread)
    {
        const uint4* g4 = (const uint4*)gtab;
        uint4* s4 = (uint4*)sTab;
#pragma unroll
        for (int i = 0; i < 8; i++) s4[tid + 256 * i] = g4[tid + 256 * i];
    }
    __syncthreads();

    const int h   = blockIdx.y;
    const int q0  = blockIdx.x * 16;
    const int wave = tid >> 6;
    const int lane = tid & 63;
    const int quad = lane >> 4;
    const int l16  = lane & 15;

    const float* Qh = Q + (size_t)h * Sn * Dn;
    const float* Kh = K + (size_t)h * Sn * Dn;
    const float* Vh = V + (size_t)h * Sn * Dn;
    const float* Dh = Dm + (size_t)h * Sn * Sn;
    const float* Eh = Em + (size_t)h * Sn * Sn;
    const int*   Mh = Mk + (size_t)h * Sn * Sn;
    const u32* tD = sTab;
    const u32* tE = sTab + TN;
    const float invhD = (float)TN / RD;
    const float invhE = (float)TN / RE;

    // Persistent Q A-fragments: A[m=l16][k = c*32 + quad*8 + j]
    const float* qrow = Qh + (q0 + l16) * Dn + quad * 8;
    const bf16x8 aQ0 = pack8(*(const float4*)(qrow),      *(const float4*)(qrow + 4));
    const bf16x8 aQ1 = pack8(*(const float4*)(qrow + 32), *(const float4*)(qrow + 36));

    f32x4 O0 = {0.f, 0.f, 0.f, 0.f}, O1 = O0, O2 = O0, O3 = O0;
    float m_r[4], l_r[4];
#pragma unroll
    for (int r = 0; r < 4; r++) { m_r[r] = -1e30f; l_r[r] = 0.f; }

    const float scale = 0.08838834764831845f;  // 1/sqrt(2*64)
    const int kbase = wave * 256;
    u16* sPw = &sP[wave][0];

    for (int t = 0; t < 8; t++) {
        const int k0 = kbase + t * 32;

        // --- K B-fragments: B[n=l16][k=quad*8+j] = K[k0+n][k] ---
        const float* kr0 = Kh + (k0 + l16) * Dn + quad * 8;
        const float* kr1 = Kh + (k0 + 16 + l16) * Dn + quad * 8;
        const bf16x8 bK00 = pack8(*(const float4*)(kr0),      *(const float4*)(kr0 + 4));
        const bf16x8 bK01 = pack8(*(const float4*)(kr0 + 32), *(const float4*)(kr0 + 36));
        const bf16x8 bK10 = pack8(*(const float4*)(kr1),      *(const float4*)(kr1 + 4));
        const bf16x8 bK11 = pack8(*(const float4*)(kr1 + 32), *(const float4*)(kr1 + 36));

        f32x4 s0 = {0.f, 0.f, 0.f, 0.f}, s1 = s0;
        s0 = __builtin_amdgcn_mfma_f32_16x16x32_bf16(aQ0, bK00, s0, 0, 0, 0);
        s0 = __builtin_amdgcn_mfma_f32_16x16x32_bf16(aQ1, bK01, s0, 0, 0, 0);
        s1 = __builtin_amdgcn_mfma_f32_16x16x32_bf16(aQ0, bK10, s1, 0, 0, 0);
        s1 = __builtin_amdgcn_mfma_f32_16x16x32_bf16(aQ1, bK11, s1, 0, 0, 0);

        // --- bias (LDS table lerp) + mask; C/D: row=quad*4+r, col=l16 ---
        float sc0[4], sc1[4];
#pragma unroll
        for (int r = 0; r < 4; r++) {
            const size_t rowoff = (size_t)(q0 + quad * 4 + r) * Sn;
            {
                const size_t off = rowoff + k0 + l16;
                float v = s0[r] * scale + lerp_tab(tD, Dh[off], invhD)
                                        + lerp_tab(tE, Eh[off], invhE);
                v = fminf(fmaxf(v, -80.f), 80.f);           // NaN/inf guard
                sc0[r] = (Mh[off] == 0) ? -1e9f : v;
            }
            {
                const size_t off = rowoff + k0 + 16 + l16;
                float v = s1[r] * scale + lerp_tab(tD, Dh[off], invhD)
                                        + lerp_tab(tE, Eh[off], invhE);
                v = fminf(fmaxf(v, -80.f), 80.f);
                sc1[r] = (Mh[off] == 0) ? -1e9f : v;
            }
        }

        // --- online softmax (row reduction across the quad's 16 lanes) ---
        float mt[4];
#pragma unroll
        for (int r = 0; r < 4; r++) mt[r] = fmaxf(sc0[r], sc1[r]);
#pragma unroll
        for (int off = 1; off < 16; off <<= 1)
#pragma unroll
            for (int r = 0; r < 4; r++)
                mt[r] = fmaxf(mt[r], __shfl_xor(mt[r], off, 16));

        float ps[4];
#pragma unroll
        for (int r = 0; r < 4; r++) {
            const float mn = fmaxf(m_r[r], mt[r]);
            const float alpha = __expf(m_r[r] - mn);
            m_r[r] = mn;
            const float p0 = __expf(sc0[r] - mn);
            const float p1 = __expf(sc1[r] - mn);
            ps[r] = p0 + p1;
            O0[r] *= alpha; O1[r] *= alpha; O2[r] *= alpha; O3[r] *= alpha;
            l_r[r] *= alpha;
            sPw[(quad * 4 + r) * 32 + l16]      = f2bf(p0);
            sPw[(quad * 4 + r) * 32 + 16 + l16] = f2bf(p1);
        }
#pragma unroll
        for (int off = 1; off < 16; off <<= 1)
#pragma unroll
            for (int r = 0; r < 4; r++)
                ps[r] += __shfl_xor(ps[r], off, 16);
#pragma unroll
        for (int r = 0; r < 4; r++) l_r[r] += ps[r];

        // --- P as A-fragment (same wave wrote it; DS ops are in-order) ---
        const bf16x8 aP = *(const bf16x8*)(sPw + l16 * 32 + quad * 8);

        // --- V B-fragments: B[n][k=quad*8+j] = V[k0+k][n] ---
        bf16x8 bV0, bV1, bV2, bV3;
#pragma unroll
        for (int j = 0; j < 8; j++) {
            const float* vr = Vh + (size_t)(k0 + quad * 8 + j) * Dn + l16;
            bV0[j] = (short)f2bf(vr[0]);
            bV1[j] = (short)f2bf(vr[16]);
            bV2[j] = (short)f2bf(vr[32]);
            bV3[j] = (short)f2bf(vr[48]);
        }
        O0 = __builtin_amdgcn_mfma_f32_16x16x32_bf16(aP, bV0, O0, 0, 0, 0);
        O1 = __builtin_amdgcn_mfma_f32_16x16x32_bf16(aP, bV1, O1, 0, 0, 0);
        O2 = __builtin_amdgcn_mfma_f32_16x16x32_bf16(aP, bV2, O2, 0, 0, 0);
        O3 = __builtin_amdgcn_mfma_f32_16x16x32_bf16(aP, bV3, O3, 0, 0, 0);
    }

    // --- cross-wave combine (flash-2) ---
#pragma unroll
    for (int r = 0; r < 4; r++) {
        if (l16 == 0) {
            sM[wave][quad * 4 + r] = m_r[r];
            sL[wave][quad * 4 + r] = l_r[r];
        }
        sOpart[wave][quad * 4 + r][0 * 16 + l16] = O0[r];
        sOpart[wave][quad * 4 + r][1 * 16 + l16] = O1[r];
        sOpart[wave][quad * 4 + r][2 * 16 + l16] = O2[r];
        sOpart[wave][quad * 4 + r][3 * 16 + l16] = O3[r];
    }
    __syncthreads();

    const int row = tid >> 4;
    const int c4  = (tid & 15) * 4;
    float mg = sM[0][row];
#pragma unroll
    for (int w = 1; w < 4; w++) mg = fmaxf(mg, sM[w][row]);
    float fac[4], lg = 0.f;
#pragma unroll
    for (int w = 0; w < 4; w++) {
        fac[w] = __expf(sM[w][row] - mg);
        lg += sL[w][row] * fac[w];
    }
    const float inv = 1.0f / lg;

    float4 ov;
    float acc[4];
#pragma unroll
    for (int c = 0; c < 4; c++) {
        acc[c] = 0.f;
#pragma unroll
        for (int w = 0; w < 4; w++) acc[c] += sOpart[w][row][c4 + c] * fac[w];
        acc[c] *= inv;
    }
    ov.x = acc[0]; ov.y = acc[1]; ov.z = acc[2]; ov.w = acc[3];
    *(float4*)(out + ((size_t)(h * Sn + q0 + row)) * Dn + c4) = ov;
}

// ---------------------------------------------------------------------------
extern "C" void kernel_launch(void* const* d_in, const int* in_sizes, int n_in,
                              void* d_out, int out_size, void* d_ws, size_t ws_size,
                              hipStream_t stream) {
    const float* Q    = (const float*)d_in[0];
    const float* K    = (const float*)d_in[1];
    const float* V    = (const float*)d_in[2];
    const float* Dm   = (const float*)d_in[3];
    const float* Em   = (const float*)d_in[4];
    const int*   Mask = (const int*)d_in[5];
    const float* muD  = (const float*)d_in[6];
    const float* sgD  = (const float*)d_in[7];
    const float* bD   = (const float*)d_in[8];
    const float* muE  = (const float*)d_in[9];
    const float* sgE  = (const float*)d_in[10];
    const float* bE   = (const float*)d_in[11];
    const float* W1   = (const float*)d_in[12];
    const float* b1   = (const float*)d_in[13];
    const float* W2   = (const float*)d_in[14];
    const float* b2   = (const float*)d_in[15];

    u32* tab = (u32*)d_ws;   // 8192 * 4 B = 32 KB (ws re-poisoned each call; rebuilt)

    build_tables_kernel<<<32, 256, 0, stream>>>(muD, sgD, bD, muE, sgE, bE,
                                                W1, b1, W2, b2, tab);

    dim3 grid(Sn / 16, Hn);
    attn_kernel<<<grid, 256, 0, stream>>>(Q, K, V, Dm, Em, Mask, tab,
                                          (float*)d_out);
}

// Round 3
// 172.684 us; speedup vs baseline: 1.3826x; 1.3826x over previous
//
#include <hip/hip_runtime.h>
#include <math.h>

// Shapes (fixed by the problem)
#define Hn 8
#define Sn 1024
#define Dn 64
#define KG 10

// Bias tables: dist in [0,10), energy in [0,5)
#define TN 2048
#define RD 10.25f
#define RE 5.125f

typedef __attribute__((ext_vector_type(8))) short bf16x8;
typedef __attribute__((ext_vector_type(4))) float f32x4;
typedef unsigned short u16;
typedef unsigned int u32;

__device__ inline float bf2f(u16 u) {
    union { u32 i; float f; } v;
    v.i = ((u32)u) << 16;
    return v.f;
}

__device__ inline u16 f2bf(float f) {
    union { float f; u32 i; } v;
    v.f = f;
    u32 i = v.i;
    return (u16)((i + 0x7FFFu + ((i >> 16) & 1u)) >> 16);   // RNE
}

// ---------------------------------------------------------------------------
// RBF (10 gaussians) -> 10x10 MLP (exact gelu) -> scalar, all f32.
// ---------------------------------------------------------------------------
__device__ float bias_eval(float x,
                           const float* __restrict__ mu, const float* __restrict__ sg,
                           const float* __restrict__ bb,
                           const float* __restrict__ W1, const float* __restrict__ b1,
                           const float* __restrict__ W2, const float* __restrict__ b2) {
    const float inv_s2pi = 0.39894228040143267794f;
    float psi[KG];
#pragma unroll
    for (int k = 0; k < KG; k++) {
        float s = sg[k];
        float z = (x + bb[k] - mu[k]) / s;
        psi[k] = __expf(-0.5f * z * z) * (inv_s2pi / s);
    }
    float out = b2[0];
#pragma unroll
    for (int l = 0; l < KG; l++) {
        float a = b1[l];
#pragma unroll
        for (int k = 0; k < KG; k++) a += psi[k] * W1[l * KG + k];
        float g = 0.5f * a * (1.0f + erff(a * 0.70710678118654752440f));
        out += g * W2[l];
    }
    return out;
}

// ---------------------------------------------------------------------------
// Fused prepass:
//  ids [0, 2*TN)                 : bias interp tables (bf16 value | bf16 delta)
//  ids [2*TN, 2*TN+262144)       : Q,K f32 -> bf16 (float4 granularity)
//  ids [2*TN+262144, +524288)    : V -> bf16, transposed [h][d][s'] with the
//                                  k-permutation matching the P register order:
//                                  s' = t*32 + q*8 + j  <->  s = t*32 + q*4 + (j&3) + 16*(j>>2)
// ---------------------------------------------------------------------------
#define QK4 262144              // (2*Hn*Sn*Dn)/4
#define VTN 524288              // Hn*Sn*Dn

__global__ __launch_bounds__(256) void prep_kernel(
    const float* __restrict__ Q, const float* __restrict__ K, const float* __restrict__ V,
    const float* __restrict__ muD, const float* __restrict__ sgD, const float* __restrict__ bD,
    const float* __restrict__ muE, const float* __restrict__ sgE, const float* __restrict__ bE,
    const float* __restrict__ W1, const float* __restrict__ b1,
    const float* __restrict__ W2, const float* __restrict__ b2,
    u32* __restrict__ tab, u16* __restrict__ Qb, u16* __restrict__ Kb, u16* __restrict__ VTi)
{
    int id = blockIdx.x * 256 + threadIdx.x;
    if (id < 2 * TN) {
        int which = (id >= TN);
        int idx = id & (TN - 1);
        float h = (which ? RE : RD) / (float)TN;
        float x0 = idx * h;
        float v0, v1;
        if (which) {
            v0 = bias_eval(x0,     muE, sgE, bE, W1, b1, W2, b2);
            v1 = bias_eval(x0 + h, muE, sgE, bE, W1, b1, W2, b2);
        } else {
            v0 = bias_eval(x0,     muD, sgD, bD, W1, b1, W2, b2);
            v1 = bias_eval(x0 + h, muD, sgD, bD, W1, b1, W2, b2);
        }
        tab[id] = (u32)f2bf(v0) | ((u32)f2bf(v1 - v0) << 16);
    } else if (id < 2 * TN + QK4) {
        int i = id - 2 * TN;
        int arr = i >> 17;          // 0 = Q, 1 = K
        i &= (1 << 17) - 1;
        float4 v = ((const float4*)(arr ? K : Q))[i];
        ushort4 o;
        o.x = f2bf(v.x); o.y = f2bf(v.y); o.z = f2bf(v.z); o.w = f2bf(v.w);
        ((ushort4*)(arr ? Kb : Qb))[i] = o;
    } else if (id < 2 * TN + QK4 + VTN) {
        int g = id - (2 * TN + QK4);
        int h = g >> 16;
        int d = (g >> 10) & 63;
        int s = g & 1023;
        int t = s >> 5, q = (s >> 3) & 3, j = s & 7;
        int src_s = (t << 5) + (q << 2) + (j & 3) + ((j >> 2) << 4);
        VTi[g] = f2bf(V[(((size_t)h << 10) + src_s) * Dn + d]);
    }
}

__device__ inline float lerp_tab(const u32* __restrict__ st, float x, float invh) {
    float tf = x * invh;
    int i = (int)tf;
    i = max(0, min(i, TN - 1));
    float fr = tf - (float)i;
    u32 p = st[i];
    return fmaf(bf2f((u16)(p >> 16)), fr, bf2f((u16)p));
}

// ---------------------------------------------------------------------------
// Fused flash attention, S^T formulation.
// Grid (S/16, H), 256 threads = 4 waves; wave w covers k in [w*256,(w+1)*256).
// QK^T computed transposed: D[kcol][qrow] -> lane's 4 regs = 4 kcols of ONE
// q-row, so bias/mask loads are float4/int4 and softmax reduction is 2 shfls.
// P stays in registers (V pre-permuted to match), no LDS roundtrip.
// ---------------------------------------------------------------------------
__global__ __launch_bounds__(256) void attn_kernel(
    const u16* __restrict__ Qb, const u16* __restrict__ Kb, const u16* __restrict__ VTi,
    const float* __restrict__ Dm, const float* __restrict__ Em, const int* __restrict__ Mk,
    const u32* __restrict__ gtab, float* __restrict__ out)
{
    __shared__ __align__(16) u32 sTab[2 * TN];      // 16 KB
    __shared__ float sO[4][16][68];                 // padded: conflict-free epilogue
    __shared__ float sM[4][16], sL[4][16];

    const int tid = threadIdx.x;
    {   // stage tables: 1024 uint4 over 256 threads
        const uint4* g4 = (const uint4*)gtab;
        uint4* s4 = (uint4*)sTab;
#pragma unroll
        for (int i = 0; i < 4; i++) s4[tid + 256 * i] = g4[tid + 256 * i];
    }
    __syncthreads();

    const int h    = blockIdx.y;
    const int q0   = blockIdx.x * 16;
    const int wave = tid >> 6;
    const int lane = tid & 63;
    const int quad = lane >> 4;
    const int l16  = lane & 15;

    const u16* Qh = Qb  + (size_t)h * Sn * Dn;
    const u16* Kh = Kb  + (size_t)h * Sn * Dn;
    const u16* Vh = VTi + (size_t)h * Dn * Sn;
    const float* Dh = Dm + (size_t)h * Sn * Sn + (size_t)(q0 + l16) * Sn;
    const float* Eh = Em + (size_t)h * Sn * Sn + (size_t)(q0 + l16) * Sn;
    const int*   Mh = Mk + (size_t)h * Sn * Sn + (size_t)(q0 + l16) * Sn;
    const float invhD = (float)TN / RD;
    const float invhE = (float)TN / RE;
    const float scale = 0.08838834764831845f;       // 1/sqrt(2*64)

    // Persistent Q B-fragments: B[n=l16][k=quad*8+j], k = d-dim
    const bf16x8 bQ0 = *(const bf16x8*)(Qh + (q0 + l16) * Dn + quad * 8);
    const bf16x8 bQ1 = *(const bf16x8*)(Qh + (q0 + l16) * Dn + 32 + quad * 8);

    f32x4 O0 = {0.f, 0.f, 0.f, 0.f}, O1 = O0, O2 = O0, O3 = O0;
    float m_run = -1e30f, l_run = 0.f;

    for (int t = 0; t < 8; t++) {
        const int k0 = wave * 256 + t * 32;

        // K A-fragments: A[m=l16][k=quad*8+j], m = kcol, k = d-dim
        const u16* kr = Kh + (size_t)(k0 + l16) * Dn + quad * 8;
        const bf16x8 aK00 = *(const bf16x8*)(kr);
        const bf16x8 aK01 = *(const bf16x8*)(kr + 32);
        const bf16x8 aK10 = *(const bf16x8*)(kr + 16 * Dn);
        const bf16x8 aK11 = *(const bf16x8*)(kr + 16 * Dn + 32);

        // bias/mask: vector loads, components map to the 4 accumulator regs
        const float4 Dv0 = *(const float4*)(Dh + k0 + quad * 4);
        const float4 Dv1 = *(const float4*)(Dh + k0 + 16 + quad * 4);
        const float4 Ev0 = *(const float4*)(Eh + k0 + quad * 4);
        const float4 Ev1 = *(const float4*)(Eh + k0 + 16 + quad * 4);
        const int4   Mv0 = *(const int4*)(Mh + k0 + quad * 4);
        const int4   Mv1 = *(const int4*)(Mh + k0 + 16 + quad * 4);

        // V B-fragments from pre-permuted V^T: contiguous 16 B loads
        const u16* vr = Vh + k0 + quad * 8;
        const bf16x8 bV0 = *(const bf16x8*)(vr + (size_t)(l16)      * Sn);
        const bf16x8 bV1 = *(const bf16x8*)(vr + (size_t)(16 + l16) * Sn);
        const bf16x8 bV2 = *(const bf16x8*)(vr + (size_t)(32 + l16) * Sn);
        const bf16x8 bV3 = *(const bf16x8*)(vr + (size_t)(48 + l16) * Sn);

        f32x4 s0 = {0.f, 0.f, 0.f, 0.f}, s1 = s0;
        s0 = __builtin_amdgcn_mfma_f32_16x16x32_bf16(aK00, bQ0, s0, 0, 0, 0);
        s0 = __builtin_amdgcn_mfma_f32_16x16x32_bf16(aK01, bQ1, s0, 0, 0, 0);
        s1 = __builtin_amdgcn_mfma_f32_16x16x32_bf16(aK10, bQ0, s1, 0, 0, 0);
        s1 = __builtin_amdgcn_mfma_f32_16x16x32_bf16(aK11, bQ1, s1, 0, 0, 0);

        const float dv0[4] = {Dv0.x, Dv0.y, Dv0.z, Dv0.w};
        const float dv1[4] = {Dv1.x, Dv1.y, Dv1.z, Dv1.w};
        const float ev0[4] = {Ev0.x, Ev0.y, Ev0.z, Ev0.w};
        const float ev1[4] = {Ev1.x, Ev1.y, Ev1.z, Ev1.w};
        const int   mv0[4] = {Mv0.x, Mv0.y, Mv0.z, Mv0.w};
        const int   mv1[4] = {Mv1.x, Mv1.y, Mv1.z, Mv1.w};

        float sc0[4], sc1[4];
#pragma unroll
        for (int r = 0; r < 4; r++) {
            float v0 = s0[r] * scale + lerp_tab(sTab, dv0[r], invhD)
                                     + lerp_tab(sTab + TN, ev0[r], invhE);
            v0 = fminf(fmaxf(v0, -80.f), 80.f);
            sc0[r] = (mv0[r] == 0) ? -1e9f : v0;
            float v1 = s1[r] * scale + lerp_tab(sTab, dv1[r], invhD)
                                     + lerp_tab(sTab + TN, ev1[r], invhE);
            v1 = fminf(fmaxf(v1, -80.f), 80.f);
            sc1[r] = (mv1[r] == 0) ? -1e9f : v1;
        }

        // row max: local over 8 values, then across quads (2 shuffles)
        float mloc = fmaxf(fmaxf(fmaxf(sc0[0], sc0[1]), fmaxf(sc0[2], sc0[3])),
                           fmaxf(fmaxf(sc1[0], sc1[1]), fmaxf(sc1[2], sc1[3])));
        mloc = fmaxf(mloc, __shfl_xor(mloc, 16, 64));
        mloc = fmaxf(mloc, __shfl_xor(mloc, 32, 64));

        const float mn = fmaxf(m_run, mloc);
        const float al = __expf(m_run - mn);
        m_run = mn;

        float p0[4], p1[4], ll = 0.f;
#pragma unroll
        for (int r = 0; r < 4; r++) {
            p0[r] = __expf(sc0[r] - mn);
            p1[r] = __expf(sc1[r] - mn);
            ll += p0[r] + p1[r];
        }
        ll += __shfl_xor(ll, 16, 64);
        ll += __shfl_xor(ll, 32, 64);
        l_run = l_run * al + ll;

        // P A-fragment straight from registers (k-order matches permuted V)
        bf16x8 aP;
#pragma unroll
        for (int r = 0; r < 4; r++) {
            aP[r]     = (short)f2bf(p0[r]);
            aP[4 + r] = (short)f2bf(p1[r]);
        }

        // O rescale: alpha for row quad*4+r lives in lane (quad*4+r)
        const float a0 = __shfl(al, quad * 4 + 0, 64);
        const float a1 = __shfl(al, quad * 4 + 1, 64);
        const float a2 = __shfl(al, quad * 4 + 2, 64);
        const float a3 = __shfl(al, quad * 4 + 3, 64);
        O0[0] *= a0; O0[1] *= a1; O0[2] *= a2; O0[3] *= a3;
        O1[0] *= a0; O1[1] *= a1; O1[2] *= a2; O1[3] *= a3;
        O2[0] *= a0; O2[1] *= a1; O2[2] *= a2; O2[3] *= a3;
        O3[0] *= a0; O3[1] *= a1; O3[2] *= a2; O3[3] *= a3;

        O0 = __builtin_amdgcn_mfma_f32_16x16x32_bf16(aP, bV0, O0, 0, 0, 0);
        O1 = __builtin_amdgcn_mfma_f32_16x16x32_bf16(aP, bV1, O1, 0, 0, 0);
        O2 = __builtin_amdgcn_mfma_f32_16x16x32_bf16(aP, bV2, O2, 0, 0, 0);
        O3 = __builtin_amdgcn_mfma_f32_16x16x32_bf16(aP, bV3, O3, 0, 0, 0);
    }

    // cross-wave combine (flash-2): O regs are [row=quad*4+r][d=vt*16+l16]
    if (lane < 16) {
        sM[wave][lane] = m_run;
        sL[wave][lane] = l_run;
    }
#pragma unroll
    for (int r = 0; r < 4; r++) {
        sO[wave][quad * 4 + r][ 0 + l16] = O0[r];
        sO[wave][quad * 4 + r][16 + l16] = O1[r];
        sO[wave][quad * 4 + r][32 + l16] = O2[r];
        sO[wave][quad * 4 + r][48 + l16] = O3[r];
    }
    __syncthreads();

    const int row = tid >> 4;
    const int c4  = (tid & 15) * 4;
    float mg = sM[0][row];
#pragma unroll
    for (int w = 1; w < 4; w++) mg = fmaxf(mg, sM[w][row]);
    float fac[4], lg = 0.f;
#pragma unroll
    for (int w = 0; w < 4; w++) {
        fac[w] = __expf(sM[w][row] - mg);
        lg += sL[w][row] * fac[w];
    }
    const float inv = 1.0f / lg;

    float acc[4];
#pragma unroll
    for (int c = 0; c < 4; c++) {
        acc[c] = 0.f;
#pragma unroll
        for (int w = 0; w < 4; w++) acc[c] += sO[w][row][c4 + c] * fac[w];
        acc[c] *= inv;
    }
    float4 ov = {acc[0], acc[1], acc[2], acc[3]};
    *(float4*)(out + ((size_t)(h * Sn + q0 + row)) * Dn + c4) = ov;
}

// ---------------------------------------------------------------------------
extern "C" void kernel_launch(void* const* d_in, const int* in_sizes, int n_in,
                              void* d_out, int out_size, void* d_ws, size_t ws_size,
                              hipStream_t stream) {
    const float* Q    = (const float*)d_in[0];
    const float* K    = (const float*)d_in[1];
    const float* V    = (const float*)d_in[2];
    const float* Dm   = (const float*)d_in[3];
    const float* Em   = (const float*)d_in[4];
    const int*   Mask = (const int*)d_in[5];
    const float* muD  = (const float*)d_in[6];
    const float* sgD  = (const float*)d_in[7];
    const float* bD   = (const float*)d_in[8];
    const float* muE  = (const float*)d_in[9];
    const float* sgE  = (const float*)d_in[10];
    const float* bE   = (const float*)d_in[11];
    const float* W1   = (const float*)d_in[12];
    const float* b1   = (const float*)d_in[13];
    const float* W2   = (const float*)d_in[14];
    const float* b2   = (const float*)d_in[15];

    // ws layout: tab 16 KB | Qb 1 MB | Kb 1 MB | VTi 1 MB  (~3.1 MB total)
    u32* tab = (u32*)d_ws;
    u16* Qb  = (u16*)((char*)d_ws + 2 * TN * 4);
    u16* Kb  = Qb + (size_t)Hn * Sn * Dn;
    u16* VTi = Kb + (size_t)Hn * Sn * Dn;

    const int prep_threads = 2 * TN + QK4 + VTN;           // 790528
    prep_kernel<<<prep_threads / 256, 256, 0, stream>>>(
        Q, K, V, muD, sgD, bD, muE, sgE, bE, W1, b1, W2, b2,
        tab, Qb, Kb, VTi);

    dim3 grid(Sn / 16, Hn);
    attn_kernel<<<grid, 256, 0, stream>>>(Qb, Kb, VTi, Dm, Em, Mask, tab,
                                          (float*)d_out);
}